// Round 3
// baseline (166.753 us; speedup 1.0000x reference)
//
#include <hip/hip_runtime.h>

#define BB 4
#define NN 512
#define EE 256
#define HH 8
#define DD 32
#define SCALING 0.17677669529663687f  // 32^-0.5
#define PR 8   // rows per proj block
#define RR 4   // rows per attn block

// ---------------------------------------------------------------------------
// Fused projection: Q (pre-scaled) [b,n,e]; K row-major per head
// Kp[((b*H+h)*N+m)*D+d]; V folded against Wf1/2/3 -> vw[((b*H+h)*3+c)*N+m].
// ---------------------------------------------------------------------------
__global__ __launch_bounds__(256) void proj_kernel(
    const float* __restrict__ query,
    const float* __restrict__ Wq, const float* __restrict__ bq,
    const float* __restrict__ Wk, const float* __restrict__ bk,
    const float* __restrict__ Wv, const float* __restrict__ bv,
    const float* __restrict__ Wf1, const float* __restrict__ Wf2,
    const float* __restrict__ Wf3,
    float* __restrict__ Q, float* __restrict__ Kp, float* __restrict__ vw)
{
    __shared__ alignas(16) float s[PR][EE];    // 8 KB
    __shared__ alignas(16) float sv[PR][EE];   // 8 KB
    const int row0 = blockIdx.x * PR;
    const int tid = threadIdx.x;               // output column e

    {
        const float4* src = (const float4*)(query + row0 * EE);
        float4* dst = (float4*)s;
        dst[tid]       = src[tid];
        dst[tid + 256] = src[tid + 256];
    }
    __syncthreads();

    float aq[PR], ak[PR], av[PR];
    #pragma unroll
    for (int r = 0; r < PR; ++r) { aq[r] = 0.f; ak[r] = 0.f; av[r] = 0.f; }

    const float4* Wq4 = (const float4*)(Wq + tid * EE);
    const float4* Wk4 = (const float4*)(Wk + tid * EE);
    const float4* Wv4 = (const float4*)(Wv + tid * EE);
    for (int j4 = 0; j4 < EE / 4; ++j4) {
        const float4 wq = Wq4[j4];
        const float4 wk = Wk4[j4];
        const float4 wv_ = Wv4[j4];
        #pragma unroll
        for (int r = 0; r < PR; ++r) {
            const float4 x = *(const float4*)&s[r][j4 * 4];
            aq[r] += x.x * wq.x + x.y * wq.y + x.z * wq.z + x.w * wq.w;
            ak[r] += x.x * wk.x + x.y * wk.y + x.z * wk.z + x.w * wk.w;
            av[r] += x.x * wv_.x + x.y * wv_.y + x.z * wv_.z + x.w * wv_.w;
        }
    }

    const float bqv = bq[tid];
    const float bkv = bk[tid];
    const float bvv = bv[tid];
    const int h = tid >> 5, d = tid & 31;
    #pragma unroll
    for (int r = 0; r < PR; ++r) {
        const int grow = row0 + r;
        const int b = grow >> 9, n = grow & 511;
        Q[grow * EE + tid] = (aq[r] + bqv) * SCALING;
        Kp[((size_t)(b * HH + h) * NN + n) * DD + d] = ak[r] + bkv;
        sv[r][tid] = av[r] + bvv;
    }
    __syncthreads();

    if (tid < PR * 24) {                       // 192 threads: (r, h, c)
        const int r = tid / 24;
        const int rem = tid % 24;
        const int hh = rem / 3;
        const int c = rem % 3;
        const float* Wf = (c == 0) ? Wf1 : ((c == 1) ? Wf2 : Wf3);
        float a = 0.f;
        #pragma unroll
        for (int dd = 0; dd < DD; ++dd)
            a += sv[r][hh * DD + dd] * Wf[hh * DD + dd];
        const int grow = row0 + r;
        const int b = grow >> 9, m = grow & 511;
        vw[((b * HH + hh) * 3 + c) * NN + m] = a;
    }
}

// ---------------------------------------------------------------------------
// Attention: 4 rows per block (512 blocks = 2/CU), thread tid = column m.
// K row for head h loaded as 8x float4 (32 VGPR), reused across 4 rows.
// No max-subtraction (|logits| ~ 8 << 88).  One barrier per head.
// ---------------------------------------------------------------------------
__global__ __launch_bounds__(512, 4) void attn_main_kernel(
    const float* __restrict__ Q, const float* __restrict__ Kp,
    const float* __restrict__ attn_bias, const float* __restrict__ vw,
    const float* __restrict__ delta_pos,
    const int* __restrict__ drop_edge_mask, const int* __restrict__ drop_or_add,
    const float* __restrict__ bf1, const float* __restrict__ bf2,
    const float* __restrict__ bf3,
    float* __restrict__ out)
{
    const int blk = blockIdx.x;                // 512 blocks
    const int b = blk >> 7;
    const int n0 = (blk & 127) * RR;
    const int tid = threadIdx.x;               // m
    const int wv_id = tid >> 6, ln = tid & 63;

    __shared__ alignas(16) float qs[RR][EE];       // 4 KB
    __shared__ alignas(16) float red[HH][RR][8];   // 1 KB
    __shared__ alignas(16) float r3[RR][3][8];

    if (tid < RR * EE / 4)
        ((float4*)qs)[tid] = ((const float4*)(Q + (b * NN + n0) * EE))[tid];
    __syncthreads();

    float acc0[RR], acc1[RR], acc2[RR];
    #pragma unroll
    for (int r = 0; r < RR; ++r) { acc0[r] = 0.f; acc1[r] = 0.f; acc2[r] = 0.f; }

    for (int h = 0; h < HH; ++h) {
        const float4* kp4 =
            (const float4*)(Kp + ((size_t)(b * HH + h) * NN + tid) * DD);
        float4 k4[DD / 4];
        #pragma unroll
        for (int j = 0; j < DD / 4; ++j) k4[j] = kp4[j];

        float p[RR];
        #pragma unroll
        for (int r = 0; r < RR; ++r) {
            float l = attn_bias[((size_t)(b * HH + h) * NN + (n0 + r)) * NN + tid];
            const float* q = &qs[r][h * DD];
            #pragma unroll
            for (int j = 0; j < DD / 4; ++j) {
                l += q[4 * j + 0] * k4[j].x + q[4 * j + 1] * k4[j].y +
                     q[4 * j + 2] * k4[j].z + q[4 * j + 3] * k4[j].w;
            }
            p[r] = __expf(l);
        }

        #pragma unroll
        for (int r = 0; r < RR; ++r) {
            float v = p[r];
            #pragma unroll
            for (int off = 32; off; off >>= 1)
                v += __shfl_xor(v, off, 64);
            if (ln == 0) red[h][r][wv_id] = v;
        }
        __syncthreads();

        const float* vwp = vw + (b * HH + h) * 3 * NN + tid;
        const float vw0 = vwp[0], vw1 = vwp[NN], vw2 = vwp[2 * NN];
        #pragma unroll
        for (int r = 0; r < RR; ++r) {
            const float4 s0 = *(const float4*)&red[h][r][0];
            const float4 s1 = *(const float4*)&red[h][r][4];
            const float sum = (s0.x + s0.y + s0.z + s0.w) +
                              (s1.x + s1.y + s1.z + s1.w);
            const float pi = p[r] * __builtin_amdgcn_rcpf(sum);
            acc0[r] += pi * vw0;
            acc1[r] += pi * vw1;
            acc2[r] += pi * vw2;
        }
        // red is indexed by h: no WAR hazard, no second barrier needed
    }

    const int doa = drop_or_add[0];
    #pragma unroll
    for (int r = 0; r < RR; ++r) {
        const float mk =
            (doa != 0 && drop_edge_mask[(n0 + r) * NN + tid] != 0) ? 0.f : 1.f;
        const float* dp = delta_pos + ((size_t)(b * NN + (n0 + r)) * NN + tid) * 3;
        float v0 = acc0[r] * dp[0] * mk;
        float v1 = acc1[r] * dp[1] * mk;
        float v2 = acc2[r] * dp[2] * mk;
        #pragma unroll
        for (int off = 32; off; off >>= 1) {
            v0 += __shfl_xor(v0, off, 64);
            v1 += __shfl_xor(v1, off, 64);
            v2 += __shfl_xor(v2, off, 64);
        }
        if (ln == 0) {
            r3[r][0][wv_id] = v0;
            r3[r][1][wv_id] = v1;
            r3[r][2][wv_id] = v2;
        }
    }
    __syncthreads();

    if (tid < RR * 3) {                        // 12 threads
        const int r = tid / 3, c = tid % 3;
        float s = 0.f;
        #pragma unroll
        for (int w = 0; w < 8; ++w) s += r3[r][c][w];
        const float bias = (c == 0) ? bf1[0] : ((c == 1) ? bf2[0] : bf3[0]);
        out[(b * NN + n0 + r) * 3 + c] = s + bias;
    }
}

// ---------------------------------------------------------------------------
extern "C" void kernel_launch(void* const* d_in, const int* in_sizes, int n_in,
                              void* d_out, int out_size, void* d_ws, size_t ws_size,
                              hipStream_t stream)
{
    const float* query          = (const float*)d_in[0];
    const float* attn_bias      = (const float*)d_in[1];
    const float* delta_pos      = (const float*)d_in[2];
    const int*   drop_edge_mask = (const int*)d_in[3];
    const float* Wq  = (const float*)d_in[4];
    const float* bq  = (const float*)d_in[5];
    const float* Wk  = (const float*)d_in[6];
    const float* bk  = (const float*)d_in[7];
    const float* Wv  = (const float*)d_in[8];
    const float* bv  = (const float*)d_in[9];
    const float* Wf1 = (const float*)d_in[10];
    const float* bf1 = (const float*)d_in[11];
    const float* Wf2 = (const float*)d_in[12];
    const float* bf2 = (const float*)d_in[13];
    const float* Wf3 = (const float*)d_in[14];
    const float* bf3 = (const float*)d_in[15];
    const int*   drop_or_add = (const int*)d_in[16];

    float* ws = (float*)d_ws;
    float* Q   = ws;                 // B*N*E   = 524288 floats
    float* Kp  = ws + 524288;        // B*H*N*D = 524288 floats
    float* vw  = ws + 1048576;       // B*H*3*N = 49152 floats

    proj_kernel<<<BB * NN / PR, 256, 0, stream>>>(query, Wq, bq, Wk, bk, Wv, bv,
                                                  Wf1, Wf2, Wf3, Q, Kp, vw);
    attn_main_kernel<<<BB * NN / RR, 512, 0, stream>>>(Q, Kp, attn_bias, vw,
                                                       delta_pos, drop_edge_mask,
                                                       drop_or_add, bf1, bf2, bf3,
                                                       (float*)d_out);
}

// Round 4
// 88.872 us; speedup vs baseline: 1.8763x; 1.8763x over previous
//
#include <hip/hip_runtime.h>

#define BB 4
#define NN 512
#define EE 256
#define HH 8
#define DD 32
#define SCALING 0.17677669529663687f  // 32^-0.5
#define PR 8   // rows per proj block
#define RR 4   // rows per attn block

// ---------------------------------------------------------------------------
// Projection, one W per block (blockIdx.y: 0=Q,1=K,2=V).  Q pre-scaled
// [b,n,e]; K row-major per head Kp[((b*H+h)*N+m)*D+d]; V folded against
// Wf1/2/3 -> vw[((b*H+h)*3+c)*N+m].  768 blocks.
// ---------------------------------------------------------------------------
__global__ __launch_bounds__(256) void proj_kernel(
    const float* __restrict__ query,
    const float* __restrict__ Wq, const float* __restrict__ bq,
    const float* __restrict__ Wk, const float* __restrict__ bk,
    const float* __restrict__ Wv, const float* __restrict__ bv,
    const float* __restrict__ Wf1, const float* __restrict__ Wf2,
    const float* __restrict__ Wf3,
    float* __restrict__ Q, float* __restrict__ Kp, float* __restrict__ vw)
{
    __shared__ alignas(16) float s[PR][EE];    // 8 KB
    __shared__ alignas(16) float sv[PR][EE];   // 8 KB (V blocks only)
    const int which = blockIdx.y;
    const int row0 = blockIdx.x * PR;
    const int tid = threadIdx.x;               // output column e

    {
        const float4* src = (const float4*)(query + row0 * EE);
        ((float4*)s)[tid]       = src[tid];
        ((float4*)s)[tid + 256] = src[tid + 256];
    }
    __syncthreads();

    const float* W  = (which == 0) ? Wq : (which == 1) ? Wk : Wv;
    const float* bb = (which == 0) ? bq : (which == 1) ? bk : bv;

    float acc[PR];
    #pragma unroll
    for (int r = 0; r < PR; ++r) acc[r] = 0.f;

    const float4* W4 = (const float4*)(W + tid * EE);
    for (int j = 0; j < EE / 4; ++j) {
        const float4 w = W4[j];
        #pragma unroll
        for (int r = 0; r < PR; ++r) {
            const float4 x = *(const float4*)&s[r][4 * j];
            acc[r] += x.x * w.x + x.y * w.y + x.z * w.z + x.w * w.w;
        }
    }
    const float bbv = bb[tid];

    if (which == 0) {
        #pragma unroll
        for (int r = 0; r < PR; ++r)
            Q[(row0 + r) * EE + tid] = (acc[r] + bbv) * SCALING;
    } else if (which == 1) {
        const int h = tid >> 5, d = tid & 31;
        #pragma unroll
        for (int r = 0; r < PR; ++r) {
            const int grow = row0 + r;
            const int b = grow >> 9, n = grow & 511;
            Kp[((size_t)(b * HH + h) * NN + n) * DD + d] = acc[r] + bbv;
        }
    } else {
        #pragma unroll
        for (int r = 0; r < PR; ++r) sv[r][tid] = acc[r] + bbv;
        __syncthreads();
        if (tid < PR * 24) {                   // 192 threads: (r, h, c)
            const int r = tid / 24;
            const int rem = tid % 24;
            const int hh = rem / 3;
            const int c = rem % 3;
            const float* Wf = (c == 0) ? Wf1 : (c == 1) ? Wf2 : Wf3;
            float a = 0.f;
            #pragma unroll
            for (int dd = 0; dd < DD; ++dd)
                a += sv[r][hh * DD + dd] * Wf[hh * DD + dd];
            const int grow = row0 + r;
            const int b = grow >> 9, m = grow & 511;
            vw[((b * HH + hh) * 3 + c) * NN + m] = a;
        }
    }
}

// ---------------------------------------------------------------------------
// Attention with post-reduction normalization:
//   out_c[b,n] = bf_c + sum_h T_c(h)/S(h),
//   S = sum_m exp(l), T_c = sum_m exp(l)*delta_c*mask*vw_c.
// Block = 4 rows, thread = column m.  No per-m state survives the reduce ->
// ~60 VGPR, no spill.  Double-buffered reduce slots -> 1 barrier per head.
// ---------------------------------------------------------------------------
__global__ __launch_bounds__(512) void attn_main_kernel(
    const float* __restrict__ Q, const float* __restrict__ Kp,
    const float* __restrict__ attn_bias, const float* __restrict__ vw,
    const float* __restrict__ delta_pos,
    const int* __restrict__ drop_edge_mask, const int* __restrict__ drop_or_add,
    const float* __restrict__ bf1, const float* __restrict__ bf2,
    const float* __restrict__ bf3,
    float* __restrict__ out)
{
    const int blk = blockIdx.x;                // 512 blocks
    const int b = blk >> 7;
    const int n0 = (blk & 127) * RR;
    const int m = threadIdx.x;                 // column m
    const int wv_id = m >> 6, ln = m & 63;

    __shared__ float red[2][4 * RR][8];        // 1 KB, double-buffered

    const int doa = drop_or_add[0];
    float dm0[RR], dm1[RR], dm2[RR];
    #pragma unroll
    for (int r = 0; r < RR; ++r) {
        const float mk =
            (doa != 0 && drop_edge_mask[(n0 + r) * NN + m] != 0) ? 0.f : 1.f;
        const float* dp = delta_pos + ((size_t)(b * NN + (n0 + r)) * NN + m) * 3;
        dm0[r] = dp[0] * mk;
        dm1[r] = dp[1] * mk;
        dm2[r] = dp[2] * mk;
    }

    float o = 0.f;                             // live only for m < 12

    for (int h = 0; h < HH; ++h) {
        const float4* kp4 =
            (const float4*)(Kp + ((size_t)((b * HH + h) * NN) + m) * DD);
        const size_t bias_base = ((size_t)(b * HH + h) * NN + n0) * NN + m;
        float l[RR];
        #pragma unroll
        for (int r = 0; r < RR; ++r) l[r] = attn_bias[bias_base + (size_t)r * NN];

        const float* qb = Q + (b * NN + n0) * EE + h * DD;  // block-uniform
        #pragma unroll
        for (int j = 0; j < DD / 4; ++j) {
            const float4 k = kp4[j];
            #pragma unroll
            for (int r = 0; r < RR; ++r) {
                const float4 q = *(const float4*)(qb + r * EE + 4 * j);
                l[r] += k.x * q.x + k.y * q.y + k.z * q.z + k.w * q.w;
            }
        }

        const float* vwp = vw + (b * HH + h) * 3 * NN + m;
        const float vw0 = vwp[0], vw1 = vwp[NN], vw2 = vwp[2 * NN];

        float vals[4 * RR];
        #pragma unroll
        for (int r = 0; r < RR; ++r) {
            const float e = __expf(l[r]);      // |l| ~ 10 << 88: no overflow
            vals[4 * r + 0] = e * dm0[r] * vw0;
            vals[4 * r + 1] = e * dm1[r] * vw1;
            vals[4 * r + 2] = e * dm2[r] * vw2;
            vals[4 * r + 3] = e;
        }

        #pragma unroll
        for (int v = 0; v < 4 * RR; ++v) {
            float x = vals[v];
            #pragma unroll
            for (int off = 32; off; off >>= 1)
                x += __shfl_xor(x, off, 64);
            vals[v] = x;
        }
        if (ln == 0) {
            #pragma unroll
            for (int v = 0; v < 4 * RR; ++v)
                red[h & 1][v][wv_id] = vals[v];
        }
        __syncthreads();

        if (m < 3 * RR) {                      // 12 threads fold this head
            const int r = m / 3, c = m % 3;
            float T = 0.f, S = 0.f;
            #pragma unroll
            for (int w = 0; w < 8; ++w) {
                T += red[h & 1][4 * r + c][w];
                S += red[h & 1][4 * r + 3][w];
            }
            o += T * __builtin_amdgcn_rcpf(S);
        }
        // next head writes the other red buffer: no extra barrier needed
    }

    if (m < 3 * RR) {
        const int r = m / 3, c = m % 3;
        const float bias = (c == 0) ? bf1[0] : (c == 1) ? bf2[0] : bf3[0];
        out[(b * NN + n0 + r) * 3 + c] = o + bias;
    }
}

// ---------------------------------------------------------------------------
extern "C" void kernel_launch(void* const* d_in, const int* in_sizes, int n_in,
                              void* d_out, int out_size, void* d_ws, size_t ws_size,
                              hipStream_t stream)
{
    const float* query          = (const float*)d_in[0];
    const float* attn_bias      = (const float*)d_in[1];
    const float* delta_pos      = (const float*)d_in[2];
    const int*   drop_edge_mask = (const int*)d_in[3];
    const float* Wq  = (const float*)d_in[4];
    const float* bq  = (const float*)d_in[5];
    const float* Wk  = (const float*)d_in[6];
    const float* bk  = (const float*)d_in[7];
    const float* Wv  = (const float*)d_in[8];
    const float* bv  = (const float*)d_in[9];
    const float* Wf1 = (const float*)d_in[10];
    const float* bf1 = (const float*)d_in[11];
    const float* Wf2 = (const float*)d_in[12];
    const float* bf2 = (const float*)d_in[13];
    const float* Wf3 = (const float*)d_in[14];
    const float* bf3 = (const float*)d_in[15];
    const int*   drop_or_add = (const int*)d_in[16];

    float* ws = (float*)d_ws;
    float* Q   = ws;                 // B*N*E   = 524288 floats
    float* Kp  = ws + 524288;        // B*H*N*D = 524288 floats
    float* vw  = ws + 1048576;       // B*H*3*N = 49152 floats

    proj_kernel<<<dim3(BB * NN / PR, 3), 256, 0, stream>>>(
        query, Wq, bq, Wk, bk, Wv, bv, Wf1, Wf2, Wf3, Q, Kp, vw);
    attn_main_kernel<<<BB * NN / RR, 512, 0, stream>>>(
        Q, Kp, attn_bias, vw, delta_pos, drop_edge_mask, drop_or_add,
        bf1, bf2, bf3, (float*)d_out);
}